// Round 2
// baseline (539.371 us; speedup 1.0000x reference)
//
#include <hip/hip_runtime.h>

// BoxCrop: crop -> aspect-preserving bilinear resize (long side = 336) ->
// square pad (fill 127). B=64, C=3, H=W=768, fp32.
//
// R2: 4 consecutive output pixels (ox) per thread. The y-side coordinate
// math (incl. one IEEE div) is shared across the 4 pixels; 48 gather loads
// per thread give high ILP; stores are aligned float4 per channel.
// Numeric op order per pixel is bit-identical to the reference.

#define OUTS 336
#define QX   84          // OUTS / 4
#define FILLV 127.0f
#define NCH  3
#define IMH  768
#define IMW  768
#define CHS  (IMH * IMW) // channel stride

__global__ __launch_bounds__(256) void boxcrop_kernel(
    const float* __restrict__ images,
    const int*   __restrict__ boxes,
    float*       __restrict__ out)
{
    const int b = blockIdx.y;
    const int t = blockIdx.x * 256 + threadIdx.x;
    if (t >= QX * OUTS) return;                 // 28224 threads/image, no barriers
    const int oy  = t / QX;
    const int ox0 = (t - oy * QX) * 4;

    // Box params uniform per block (b = blockIdx.y) -> scalar loads.
    const int xb = boxes[4 * b + 0];
    const int yb = boxes[4 * b + 1];
    const int wb = boxes[4 * b + 2];
    const int hb = boxes[4 * b + 3];

    const float wf = (float)wb;
    const float hf = (float)hb;
    const float scale = 336.0f / fmaxf(wf, hf);
    const int new_w = (int)rintf(wf * scale);   // rintf == round-half-even
    const int new_h = (int)rintf(hf * scale);
    const int pad_top  = (hb < wb)  ? ((OUTS - new_h) >> 1) : 0;
    const int pad_left = (hb >= wb) ? ((OUTS - new_w) >> 1) : 0;

    float res[NCH][4];
    #pragma unroll
    for (int c = 0; c < NCH; ++c)
        #pragma unroll
        for (int i = 0; i < 4; ++i)
            res[c][i] = FILLV;

    const int iy = oy - pad_top;
    if (iy >= 0 && iy < new_h) {
        // y-side math shared by the 4 pixels (exact reference op order)
        const float src_y = ((float)yb + (((float)iy + 0.5f) * hf) / (float)new_h) - 0.5f;
        const float y0f = floorf(src_y);
        const float wy   = src_y - y0f;
        const float omwy = 1.0f - wy;
        const int yhi = yb + hb - 1;
        const int y0 = min(max((int)y0f,     yb), yhi);
        const int y1 = min(max((int)y0f + 1, yb), yhi);

        const size_t img_base = (size_t)b * (NCH * (size_t)CHS);
        const size_t row0 = img_base + (size_t)y0 * IMW;
        const size_t row1 = img_base + (size_t)y1 * IMW;
        const int xhi = xb + wb - 1;

        #pragma unroll
        for (int i = 0; i < 4; ++i) {
            const int ix = ox0 + i - pad_left;
            if (ix >= 0 && ix < new_w) {
                const float src_x = ((float)xb + (((float)ix + 0.5f) * wf) / (float)new_w) - 0.5f;
                const float x0f = floorf(src_x);
                const float wx   = src_x - x0f;
                const float omwx = 1.0f - wx;
                const int x0 = min(max((int)x0f,     xb), xhi);
                const int x1 = min(max((int)x0f + 1, xb), xhi);

                #pragma unroll
                for (int c = 0; c < NCH; ++c) {
                    const float* img = images + (size_t)c * CHS;
                    const float v00 = img[row0 + x0];
                    const float v01 = img[row0 + x1];
                    const float v10 = img[row1 + x0];
                    const float v11 = img[row1 + x1];
                    const float top = v00 * omwx + v01 * wx;
                    const float bot = v10 * omwx + v11 * wx;
                    res[c][i] = top * omwy + bot * wy;
                }
            }
        }
    }

    // Aligned float4 stores (ox0 % 4 == 0)
    float* ob = out + (size_t)b * (NCH * (size_t)(OUTS * OUTS)) + (size_t)oy * OUTS + ox0;
    #pragma unroll
    for (int c = 0; c < NCH; ++c) {
        float4 v = make_float4(res[c][0], res[c][1], res[c][2], res[c][3]);
        *(float4*)(ob + (size_t)c * (OUTS * OUTS)) = v;
    }
}

extern "C" void kernel_launch(void* const* d_in, const int* in_sizes, int n_in,
                              void* d_out, int out_size, void* d_ws, size_t ws_size,
                              hipStream_t stream) {
    const float* images = (const float*)d_in[0];
    const int*   boxes  = (const int*)d_in[1];
    float*       out    = (float*)d_out;

    const int B = in_sizes[1] / 4;          // boxes is [B,4] int32
    const int tpi = QX * OUTS;              // 28224 threads per image
    dim3 grid((tpi + 255) / 256, B, 1);     // 111 x B (tail masked)
    dim3 block(256, 1, 1);
    boxcrop_kernel<<<grid, block, 0, stream>>>(images, boxes, out);
}